// Round 3
// baseline (182.492 us; speedup 1.0000x reference)
//
#include <hip/hip_runtime.h>
#include <hip/hip_bf16.h>

#define NROWS 16384
#define DIN   4096
#define DOUT  4096
#define RNK   64
#define EPSF  1e-7f

typedef float  f32x4  __attribute__((ext_vector_type(4)));
typedef __bf16 bf16x4 __attribute__((ext_vector_type(4)));
typedef __bf16 bf16x8 __attribute__((ext_vector_type(8)));

__device__ __forceinline__ bf16x8 cvt8(f32x4 a, f32x4 b) {
    bf16x8 r;
    r[0]=(__bf16)a.x; r[1]=(__bf16)a.y; r[2]=(__bf16)a.z; r[3]=(__bf16)a.w;
    r[4]=(__bf16)b.x; r[5]=(__bf16)b.y; r[6]=(__bf16)b.z; r[7]=(__bf16)b.w;
    return r;
}

// ---------------------------------------------------------------------------
// KB: per-256-row B slice: bf16-convert, emit Bpf in MFMA-fragment order,
//     and Gram partials. Bpf chunk C=(j*2+ks)*64+l holds
//     B[j*16+(l&15)][ks*32+(l>>4)*8 + 0..7]  (j = 16-col out tile).
// ---------------------------------------------------------------------------
__global__ __launch_bounds__(512, 4)
void kb_gram(const float* __restrict__ Bw, __bf16* __restrict__ Bpf,
             float* __restrict__ Gpart) {
    __shared__ __bf16 bs[256][72];
    const int t = threadIdx.x;
    const int jb = blockIdx.x * 256;

    {   // stage + convert: thread t -> row t>>1, cols (t&1)*32..+31
        const int j0 = t >> 1, c0 = (t & 1) * 32;
        #pragma unroll
        for (int u = 0; u < 4; ++u) {
            f32x4 v0 = *(const f32x4*)&Bw[(size_t)(jb + j0) * RNK + c0 + 8*u];
            f32x4 v1 = *(const f32x4*)&Bw[(size_t)(jb + j0) * RNK + c0 + 8*u + 4];
            *(bf16x8*)&bs[j0][c0 + 8*u] = cvt8(v0, v1);
        }
    }
    __syncthreads();

    // fragment-order write-back: 16 jl x 2 ks x 64 l = 2048 chunks / block
    #pragma unroll
    for (int u = 0; u < 4; ++u) {
        const int lc = t + 512 * u;
        const int ll = lc & 63;
        const int ks = (lc >> 6) & 1;
        const int jl = lc >> 7;
        bf16x8 v = *(const bf16x8*)&bs[jl * 16 + (ll & 15)][ks * 32 + (ll >> 4) * 8];
        const size_t C = ((size_t)((jb >> 4) + jl) * 2 + ks) * 64 + ll;
        *(bf16x8*)&Bpf[C * 8] = v;
    }

    // Gram partial: thread t owns (r = t&63, r' = (t>>6)*8..+7)
    const int r = t & 63, rp = (t >> 6) * 8;
    float acc[8] = {0,0,0,0,0,0,0,0};
    for (int j = 0; j < 256; ++j) {
        float s = (float)bs[j][r];
        bf16x8 v = *(const bf16x8*)&bs[j][rp];   // wave-uniform: broadcast
        #pragma unroll
        for (int u = 0; u < 8; ++u) acc[u] += s * (float)v[u];
    }
    #pragma unroll
    for (int u = 0; u < 8; ++u)
        Gpart[(size_t)blockIdx.x * 4096 + r * 64 + rp + u] = acc[u];
}

__global__ void kc0_sum(const float* __restrict__ Gpart, float* __restrict__ G) {
    const int t = threadIdx.x;   // 256 thr, 16 f32 each
    #pragma unroll
    for (int v = 0; v < 4; ++v) {
        f32x4 a = {0.f, 0.f, 0.f, 0.f};
        for (int b = 0; b < 16; ++b)
            a += *(const f32x4*)&Gpart[(size_t)b * 4096 + t * 16 + v * 4];
        *(f32x4*)&G[t * 16 + v * 4] = a;
    }
}

// ---------------------------------------------------------------------------
// Fused: per 32-row tile:
//   GEMM1 (x @ Aw^T, bf16 MFMA, fused row-sumsq) -> sinh scale ->
//   r2 = s1^T G s1 (f32 in LDS) -> g -> s1pf (bf16, fragment order) ->
//   GEMM2 over all 4096 cols, B fragments straight from L2, no barriers.
// ---------------------------------------------------------------------------
#define LPK 136
__global__ __launch_bounds__(512, 4)
void kfused(const float* __restrict__ x, const float* __restrict__ Aw,
            const float* __restrict__ G, const __bf16* __restrict__ Bpf,
            float* __restrict__ out) {
    __shared__ __bf16 xs[32][LPK];          // 8.7 KB
    __shared__ __bf16 as[64][LPK];          // 17.4 KB
    __shared__ float  Gs[64][64];           // 16 KB  (read as [r][lane]: conflict-free)
    __shared__ float  s1f[32][64];          // 8 KB
    __shared__ __bf16 s1pf[2][2][64][8];    // 4 KB   [m-group][ks][lane][8]
    __shared__ float  rowss[32];
    __shared__ float  gs[32];

    const int t = threadIdx.x;
    const int l = t & 63;
    const int w = t >> 6;
    const int brow = blockIdx.x * 32;

    {   // stage G: 4096 f32 / 512 thr = 8 each (visible by first barrier)
        float* gf = &Gs[0][0];
        *(f32x4*)&gf[t * 8]     = *(const f32x4*)&G[t * 8];
        *(f32x4*)&gf[t * 8 + 4] = *(const f32x4*)&G[t * 8 + 4];
    }

    // ---- GEMM1 ----
    const int xrow = t >> 4, xcol = (t & 15) * 8;   // x: 32x128
    const int arow = t >> 3, acol = (t & 7) * 16;   // A: 64x128
    const size_t xb = (size_t)(brow + xrow) * DIN + xcol;
    const size_t ab = (size_t)arow * DIN + acol;

    const int m0   = (w & 1) * 16;
    const int n0   = (w >> 1) * 16;
    const int frow = l & 15;
    const int koff = (l >> 4) * 8;

    float ssq = 0.f;
    f32x4 acc = {0.f, 0.f, 0.f, 0.f};
    f32x4 xA0,xA1,aA0,aA1,aA2,aA3, xB0,xB1,aB0,aB1,aB2,aB3;

    auto load = [&](f32x4&x0,f32x4&x1,f32x4&A0,f32x4&A1,f32x4&A2,f32x4&A3,int kt){
        const size_t o = (size_t)kt * 128;
        x0 = *(const f32x4*)&x[xb + o];       x1 = *(const f32x4*)&x[xb + o + 4];
        A0 = *(const f32x4*)&Aw[ab + o];      A1 = *(const f32x4*)&Aw[ab + o + 4];
        A2 = *(const f32x4*)&Aw[ab + o + 8];  A3 = *(const f32x4*)&Aw[ab + o + 12];
    };
    auto consume = [&](const f32x4&x0,const f32x4&x1,const f32x4&A0,
                       const f32x4&A1,const f32x4&A2,const f32x4&A3){
        ssq += x0.x*x0.x + x0.y*x0.y + x0.z*x0.z + x0.w*x0.w;
        ssq += x1.x*x1.x + x1.y*x1.y + x1.z*x1.z + x1.w*x1.w;
        *(bf16x8*)&xs[xrow][xcol]     = cvt8(x0, x1);
        *(bf16x8*)&as[arow][acol]     = cvt8(A0, A1);
        *(bf16x8*)&as[arow][acol + 8] = cvt8(A2, A3);
        __syncthreads();
        #pragma unroll
        for (int ks = 0; ks < 4; ++ks) {
            bf16x8 af  = *(const bf16x8*)&xs[m0 + frow][ks*32 + koff];
            bf16x8 bf_ = *(const bf16x8*)&as[n0 + frow][ks*32 + koff];
            acc = __builtin_amdgcn_mfma_f32_16x16x32_bf16(af, bf_, acc, 0, 0, 0);
        }
        __syncthreads();
    };

    const int NT = DIN / 128;   // 32
    load(xA0,xA1,aA0,aA1,aA2,aA3, 0);
    for (int kt = 0; kt < NT; kt += 2) {
        load(xB0,xB1,aB0,aB1,aB2,aB3, kt + 1);
        consume(xA0,xA1,aA0,aA1,aA2,aA3);
        if (kt + 2 < NT) load(xA0,xA1,aA0,aA1,aA2,aA3, kt + 2);
        consume(xB0,xB1,aB0,aB1,aB2,aB3);
    }

    // ---- sinh scale ----
    ssq += __shfl_xor(ssq, 1);
    ssq += __shfl_xor(ssq, 2);
    ssq += __shfl_xor(ssq, 4);
    ssq += __shfl_xor(ssq, 8);
    if ((l & 15) == 0) rowss[w * 4 + (l >> 4)] = ssq;
    __syncthreads();
    if (t < 32) {
        float vn = fmaxf(sqrtf(rowss[t]), EPSF);
        rowss[t] = sinhf(vn) / vn;
    }
    __syncthreads();

    // ---- scaled s1 (f32) to LDS ----
    #pragma unroll
    for (int q = 0; q < 4; ++q) {
        const int row = m0 + (l >> 4) * 4 + q;
        s1f[row][n0 + frow] = rowss[row] * acc[q];
    }
    __syncthreads();

    // ---- r2 = s1^T G s1 per row; wave w owns rows 4w..4w+3 ----
    {
        const int r0 = w * 4;
        float y0=0.f, y1=0.f, y2=0.f, y3=0.f;
        for (int r = 0; r < 64; ++r) {
            const float gr = Gs[r][l];          // lanes consecutive: conflict-free
            y0 += gr * s1f[r0 + 0][r];          // wave-uniform: broadcast
            y1 += gr * s1f[r0 + 1][r];
            y2 += gr * s1f[r0 + 2][r];
            y3 += gr * s1f[r0 + 3][r];
        }
        float q0 = s1f[r0 + 0][l] * y0;
        float q1 = s1f[r0 + 1][l] * y1;
        float q2 = s1f[r0 + 2][l] * y2;
        float q3 = s1f[r0 + 3][l] * y3;
        #pragma unroll
        for (int s = 1; s < 64; s <<= 1) {
            q0 += __shfl_xor(q0, s);
            q1 += __shfl_xor(q1, s);
            q2 += __shfl_xor(q2, s);
            q3 += __shfl_xor(q3, s);
        }
        if (l == 0) {
            float r2v[4] = {q0, q1, q2, q3};
            #pragma unroll
            for (int i = 0; i < 4; ++i) {
                const float r2 = r2v[i];
                const float rn = sqrtf(r2);
                gs[r0 + i] = 0.25f * acoshf(fmaxf(sqrtf(1.f + r2), 1.f + EPSF))
                                   / fmaxf(rn, EPSF);
            }
        }
    }
    __syncthreads();

    // ---- build s1pf (bf16, fragment order, g folded in) ----
    if (t < 256) {
        const int ll = t & 63, ksq = (t >> 6) & 1, mg = t >> 7;
        const int row = mg * 16 + (ll & 15);
        const int kc  = ksq * 32 + (ll >> 4) * 8;
        const float gg = gs[row];
        bf16x8 p;
        #pragma unroll
        for (int u = 0; u < 8; ++u) p[u] = (__bf16)(gg * s1f[row][kc + u]);
        *(bf16x8*)&s1pf[mg][ksq][ll][0] = p;
    }
    __syncthreads();

    // ---- GEMM2: barrier-free, B fragments straight from L2 ----
    {
        const int mg = w & 1;
        const int mr0 = mg * 16;
        const bf16x8 a0f = *(const bf16x8*)&s1pf[mg][0][l][0];
        const bf16x8 a1f = *(const bf16x8*)&s1pf[mg][1][l][0];
        #pragma unroll 4
        for (int jj = 0; jj < 64; ++jj) {
            const int j = (w >> 1) + jj * 4;
            const size_t base = ((size_t)j * 2 * 64 + l) * 8;
            bf16x8 b0 = *(const bf16x8*)&Bpf[base];
            bf16x8 b1 = *(const bf16x8*)&Bpf[base + 512];
            f32x4 a2 = {0.f, 0.f, 0.f, 0.f};
            a2 = __builtin_amdgcn_mfma_f32_16x16x32_bf16(a0f, b0, a2, 0, 0, 0);
            a2 = __builtin_amdgcn_mfma_f32_16x16x32_bf16(a1f, b1, a2, 0, 0, 0);
            const int col = j * 16 + frow;
            #pragma unroll
            for (int q = 0; q < 4; ++q) {
                const int row = mr0 + (l >> 4) * 4 + q;
                out[(size_t)(brow + row) * DOUT + col] = a2[q];
            }
        }
    }
}

extern "C" void kernel_launch(void* const* d_in, const int* in_sizes, int n_in,
                              void* d_out, int out_size, void* d_ws, size_t ws_size,
                              hipStream_t stream) {
    const float* x  = (const float*)d_in[0];   // (16384, 4096)
    const float* Aw = (const float*)d_in[1];   // (64, 4096)
    const float* Bw = (const float*)d_in[2];   // (4096, 64)
    float* out = (float*)d_out;

    char* ws = (char*)d_ws;
    __bf16* Bpf   = (__bf16*)(ws);              // 512 KB (fragment order)
    float*  Gpart = (float*)(ws + 524288);      // 256 KB
    float*  G     = (float*)(ws + 786432);      // 16 KB

    kb_gram<<<16, 512, 0, stream>>>(Bw, Bpf, Gpart);
    kc0_sum<<<1, 256, 0, stream>>>(Gpart, G);
    kfused<<<NROWS / 32, 512, 0, stream>>>(x, Aw, G, Bpf, out);
}